// Round 1
// baseline (6179.525 us; speedup 1.0000x reference)
//
#include <hip/hip_runtime.h>
#include <hip/hip_bf16.h>
#include <math.h>

// Problem constants (B=2, S=2048, D=1024, H=16, hd=64)
#define B_  2
#define S_  2048
#define D_  1024
#define H_  16
#define HD_ 64
// qkv row stride = 3*D = 3072

// ---------------------------------------------------------------------------
// Generic fp32 tiled GEMM: C[M,N] = A[M,K] @ B[K,N], all row-major.
// 64x64 tile, BK=16, 256 threads, 4x4 micro-tile per thread.
// M,N multiples of 64; K multiple of 16.
// ---------------------------------------------------------------------------
__global__ __launch_bounds__(256) void gemm_f32(
    const float* __restrict__ A, const float* __restrict__ Bm,
    float* __restrict__ C, int M, int N, int K)
{
    __shared__ float As[16][68];   // [k][m], padded to break bank conflicts
    __shared__ float Bs[16][64];   // [k][n]

    const int tid = threadIdx.x;
    const int tx = tid & 15;       // micro-tile col group
    const int ty = tid >> 4;       // micro-tile row group
    const int row0 = blockIdx.y * 64;
    const int col0 = blockIdx.x * 64;

    float acc[4][4];
#pragma unroll
    for (int i = 0; i < 4; ++i)
#pragma unroll
        for (int j = 0; j < 4; ++j) acc[i][j] = 0.f;

    const int am = tid >> 2;            // 0..63 : A row within tile
    const int ak = (tid & 3) * 4;       // 0..12 : A col (k) within tile
    const int bk = tid >> 4;            // 0..15 : B row (k) within tile
    const int bn = (tid & 15) * 4;      // 0..60 : B col within tile

    for (int k0 = 0; k0 < K; k0 += 16) {
        float4 a4 = *(const float4*)(A + (size_t)(row0 + am) * K + k0 + ak);
        float4 b4 = *(const float4*)(Bm + (size_t)(k0 + bk) * N + col0 + bn);
        As[ak + 0][am] = a4.x;
        As[ak + 1][am] = a4.y;
        As[ak + 2][am] = a4.z;
        As[ak + 3][am] = a4.w;
        *(float4*)&Bs[bk][bn] = b4;
        __syncthreads();

#pragma unroll
        for (int kk = 0; kk < 16; ++kk) {
            float a0 = As[kk][ty * 4 + 0];
            float a1 = As[kk][ty * 4 + 1];
            float a2 = As[kk][ty * 4 + 2];
            float a3 = As[kk][ty * 4 + 3];
            float4 bb = *(float4*)&Bs[kk][tx * 4];
            acc[0][0] = fmaf(a0, bb.x, acc[0][0]);
            acc[0][1] = fmaf(a0, bb.y, acc[0][1]);
            acc[0][2] = fmaf(a0, bb.z, acc[0][2]);
            acc[0][3] = fmaf(a0, bb.w, acc[0][3]);
            acc[1][0] = fmaf(a1, bb.x, acc[1][0]);
            acc[1][1] = fmaf(a1, bb.y, acc[1][1]);
            acc[1][2] = fmaf(a1, bb.z, acc[1][2]);
            acc[1][3] = fmaf(a1, bb.w, acc[1][3]);
            acc[2][0] = fmaf(a2, bb.x, acc[2][0]);
            acc[2][1] = fmaf(a2, bb.y, acc[2][1]);
            acc[2][2] = fmaf(a2, bb.z, acc[2][2]);
            acc[2][3] = fmaf(a2, bb.w, acc[2][3]);
            acc[3][0] = fmaf(a3, bb.x, acc[3][0]);
            acc[3][1] = fmaf(a3, bb.y, acc[3][1]);
            acc[3][2] = fmaf(a3, bb.z, acc[3][2]);
            acc[3][3] = fmaf(a3, bb.w, acc[3][3]);
        }
        __syncthreads();
    }

#pragma unroll
    for (int i = 0; i < 4; ++i) {
        float4 o = make_float4(acc[i][0], acc[i][1], acc[i][2], acc[i][3]);
        *(float4*)(C + (size_t)(row0 + ty * 4 + i) * N + col0 + tx * 4) = o;
    }
}

// ---------------------------------------------------------------------------
// RoPE applied in-place to the q and k thirds of the qkv buffer.
// qkv layout: [B*S, 3*D]; head h occupies cols h*64..h*64+63 of each third.
// One thread per (row m, head h, pair j) with j in [0,32).
// q'[j]    = q[j]*cos - q[j+32]*sin
// q'[j+32] = q[j+32]*cos + q[j]*sin     (same for k)
// ---------------------------------------------------------------------------
__global__ __launch_bounds__(256) void rope_kernel(float* __restrict__ qkv)
{
    int idx = blockIdx.x * 256 + threadIdx.x;   // < 4096*16*32
    int j = idx & 31;
    int h = (idx >> 5) & (H_ - 1);
    int m = idx >> 9;                            // row in [0, B*S)
    int s = m & (S_ - 1);                        // position

    float inv = powf(10000.0f, -(float)j * (1.0f / 32.0f));
    float ang = (float)s * inv;
    float sn, cs;
    sincosf(ang, &sn, &cs);   // precise version: ang can be ~2047 rad

    size_t base = (size_t)m * 3072 + h * 64 + j;
    float q1 = qkv[base];
    float q2 = qkv[base + 32];
    qkv[base]      = q1 * cs - q2 * sn;
    qkv[base + 32] = q2 * cs + q1 * sn;

    float k1 = qkv[base + 1024];
    float k2 = qkv[base + 1056];
    qkv[base + 1024] = k1 * cs - k2 * sn;
    qkv[base + 1056] = k2 * cs + k1 * sn;
}

// ---------------------------------------------------------------------------
// Causal attention, flash-style online softmax.
// Block = 256 threads = 4 waves; each wave owns one query row (lane = hd dim).
// K/V tiles of 64 keys staged in LDS, shared by the 4 waves.
// grid = (S/4, B*H)
// Output layout: out[b, s, h*64 + d]  (== transpose(0,2,1,3).reshape)
// ---------------------------------------------------------------------------
__global__ __launch_bounds__(256) void attn_kernel(
    const float* __restrict__ qkv, float* __restrict__ out)
{
    __shared__ float Ks[64][64];
    __shared__ float Vs[64][64];

    const int bh = blockIdx.y;
    const int b = bh >> 4;
    const int h = bh & (H_ - 1);
    const int q_base = blockIdx.x * 4;
    const int wave = threadIdx.x >> 6;
    const int lane = threadIdx.x & 63;
    const int q_idx = q_base + wave;

    // q for this wave, scale folded in (scores = (q.k)/sqrt(64))
    const float* qrow = qkv + (size_t)(b * S_ + q_idx) * 3072 + h * 64;
    float qd = qrow[lane] * 0.125f;

    float m = -INFINITY, l = 0.f, acc = 0.f;

    const int n_tiles = (q_base + 3) / 64 + 1;   // last tile containing q_base+3
    const int key_l = threadIdx.x >> 2;          // 0..63 : key within tile
    const int db = (threadIdx.x & 3) * 16;       // 0..48 : dim offset

    for (int t = 0; t < n_tiles; ++t) {
        __syncthreads();
        const float* kg = qkv + (size_t)(b * S_ + t * 64 + key_l) * 3072
                          + 1024 + h * 64 + db;
#pragma unroll
        for (int c = 0; c < 16; c += 4) {
            *(float4*)&Ks[key_l][db + c] = *(const float4*)(kg + c);
            *(float4*)&Vs[key_l][db + c] = *(const float4*)(kg + 1024 + c);
        }
        __syncthreads();

        int kmax = min(63, q_idx - t * 64);      // causal bound within tile
        for (int j = 0; j <= kmax; ++j) {
            float prod = qd * Ks[j][lane];
#pragma unroll
            for (int off = 32; off > 0; off >>= 1)
                prod += __shfl_xor(prod, off, 64);
            float s = prod;                       // full dot, all lanes
            float mn = fmaxf(m, s);
            float alpha = __expf(m - mn);         // exp(-inf)=0 on first iter
            float p = __expf(s - mn);
            l = l * alpha + p;
            acc = acc * alpha + p * Vs[j][lane];
            m = mn;
        }
    }

    out[(size_t)(b * S_ + q_idx) * 1024 + h * 64 + lane] = acc / l;
}

// ---------------------------------------------------------------------------
extern "C" void kernel_launch(void* const* d_in, const int* in_sizes, int n_in,
                              void* d_out, int out_size, void* d_ws, size_t ws_size,
                              hipStream_t stream)
{
    const float* x     = (const float*)d_in[0];   // [2,2048,1024]
    const float* w_qkv = (const float*)d_in[1];   // [1024,3072]
    const float* w_out = (const float*)d_in[2];   // [1024,1024]
    float* out = (float*)d_out;                   // [2,2048,1024]

    float* qkv  = (float*)d_ws;                        // 4096*3072 floats (50.3 MB)
    float* attn = qkv + (size_t)4096 * 3072;           // 4096*1024 floats (16.8 MB)

    // 1) qkv = x @ w_qkv
    gemm_f32<<<dim3(3072 / 64, 4096 / 64), 256, 0, stream>>>(
        x, w_qkv, qkv, 4096, 3072, 1024);

    // 2) RoPE in place on q,k
    rope_kernel<<<(4096 * 16 * 32) / 256, 256, 0, stream>>>(qkv);

    // 3) causal attention -> attn [B*S, D] with (h,d) packed
    attn_kernel<<<dim3(S_ / 4, B_ * H_), 256, 0, stream>>>(qkv, attn);

    // 4) out = attn @ w_out
    gemm_f32<<<dim3(1024 / 64, 4096 / 64), 256, 0, stream>>>(
        attn, w_out, out, 4096, 1024, 1024);
}

// Round 2
// 2310.449 us; speedup vs baseline: 2.6746x; 2.6746x over previous
//
#include <hip/hip_runtime.h>
#include <hip/hip_bf16.h>
#include <math.h>

// Problem constants (B=2, S=2048, D=1024, H=16, hd=64)
#define B_  2
#define S_  2048
#define D_  1024
#define H_  16
#define HD_ 64
// qkv row stride = 3*D = 3072

// ---------------------------------------------------------------------------
// Generic fp32 tiled GEMM: C[M,N] = A[M,K] @ B[K,N], all row-major.
// 64x64 tile, BK=16, 256 threads, 4x4 micro-tile per thread.
// ---------------------------------------------------------------------------
__global__ __launch_bounds__(256) void gemm_f32(
    const float* __restrict__ A, const float* __restrict__ Bm,
    float* __restrict__ C, int M, int N, int K)
{
    __shared__ float As[16][68];   // [k][m], padded
    __shared__ float Bs[16][64];   // [k][n]

    const int tid = threadIdx.x;
    const int tx = tid & 15;
    const int ty = tid >> 4;
    const int row0 = blockIdx.y * 64;
    const int col0 = blockIdx.x * 64;

    float acc[4][4];
#pragma unroll
    for (int i = 0; i < 4; ++i)
#pragma unroll
        for (int j = 0; j < 4; ++j) acc[i][j] = 0.f;

    const int am = tid >> 2;
    const int ak = (tid & 3) * 4;
    const int bk = tid >> 4;
    const int bn = (tid & 15) * 4;

    for (int k0 = 0; k0 < K; k0 += 16) {
        float4 a4 = *(const float4*)(A + (size_t)(row0 + am) * K + k0 + ak);
        float4 b4 = *(const float4*)(Bm + (size_t)(k0 + bk) * N + col0 + bn);
        As[ak + 0][am] = a4.x;
        As[ak + 1][am] = a4.y;
        As[ak + 2][am] = a4.z;
        As[ak + 3][am] = a4.w;
        *(float4*)&Bs[bk][bn] = b4;
        __syncthreads();

#pragma unroll
        for (int kk = 0; kk < 16; ++kk) {
            float a0 = As[kk][ty * 4 + 0];
            float a1 = As[kk][ty * 4 + 1];
            float a2 = As[kk][ty * 4 + 2];
            float a3 = As[kk][ty * 4 + 3];
            float4 bb = *(float4*)&Bs[kk][tx * 4];
            acc[0][0] = fmaf(a0, bb.x, acc[0][0]);
            acc[0][1] = fmaf(a0, bb.y, acc[0][1]);
            acc[0][2] = fmaf(a0, bb.z, acc[0][2]);
            acc[0][3] = fmaf(a0, bb.w, acc[0][3]);
            acc[1][0] = fmaf(a1, bb.x, acc[1][0]);
            acc[1][1] = fmaf(a1, bb.y, acc[1][1]);
            acc[1][2] = fmaf(a1, bb.z, acc[1][2]);
            acc[1][3] = fmaf(a1, bb.w, acc[1][3]);
            acc[2][0] = fmaf(a2, bb.x, acc[2][0]);
            acc[2][1] = fmaf(a2, bb.y, acc[2][1]);
            acc[2][2] = fmaf(a2, bb.z, acc[2][2]);
            acc[2][3] = fmaf(a2, bb.w, acc[2][3]);
            acc[3][0] = fmaf(a3, bb.x, acc[3][0]);
            acc[3][1] = fmaf(a3, bb.y, acc[3][1]);
            acc[3][2] = fmaf(a3, bb.z, acc[3][2]);
            acc[3][3] = fmaf(a3, bb.w, acc[3][3]);
        }
        __syncthreads();
    }

#pragma unroll
    for (int i = 0; i < 4; ++i) {
        float4 o = make_float4(acc[i][0], acc[i][1], acc[i][2], acc[i][3]);
        *(float4*)(C + (size_t)(row0 + ty * 4 + i) * N + col0 + tx * 4) = o;
    }
}

// ---------------------------------------------------------------------------
// RoPE in-place on q,k thirds of qkv. One thread per (row, head, pair).
// ---------------------------------------------------------------------------
__global__ __launch_bounds__(256) void rope_kernel(float* __restrict__ qkv)
{
    int idx = blockIdx.x * 256 + threadIdx.x;
    int j = idx & 31;
    int h = (idx >> 5) & (H_ - 1);
    int m = idx >> 9;
    int s = m & (S_ - 1);

    float inv = powf(10000.0f, -(float)j * (1.0f / 32.0f));
    float ang = (float)s * inv;
    float sn, cs;
    sincosf(ang, &sn, &cs);

    size_t base = (size_t)m * 3072 + h * 64 + j;
    float q1 = qkv[base];
    float q2 = qkv[base + 32];
    qkv[base]      = q1 * cs - q2 * sn;
    qkv[base + 32] = q2 * cs + q1 * sn;

    float k1 = qkv[base + 1024];
    float k2 = qkv[base + 1056];
    qkv[base + 1024] = k1 * cs - k2 * sn;
    qkv[base + 1056] = k2 * cs + k1 * sn;
}

// ---------------------------------------------------------------------------
// Causal attention, flash-style, tile-parallel scores.
// Block = 256 threads = 4 waves; wave owns one query. 64-key K/V LDS tiles
// shared by the 4 waves. Per tile:
//   Phase A: lane = key j -> s_j = sum_d q_d * K[j][d]   (q in registers)
//   softmax bookkeeping once per tile (max-reduce, sum-reduce, one rescale)
//   Phase B: lane = dim d -> acc_d = acc_d*alpha + sum_j p_j * V[j][d]
// Ks/Vs stride 65: bank = (j+d) mod 32 -> 2 lanes/bank in both phases = free.
// Staging writes are scalar (stride-65 rows are not 16B-aligned).
// grid = (S/4, B*H)
// ---------------------------------------------------------------------------
__global__ __launch_bounds__(256) void attn_kernel(
    const float* __restrict__ qkv, float* __restrict__ out)
{
    __shared__ float Ks[64][65];
    __shared__ float Vs[64][65];
    __shared__ float qs[4][64];

    const int bh = blockIdx.y;
    const int b = bh >> 4;
    const int h = bh & (H_ - 1);
    const int q_base = blockIdx.x * 4;
    const int wave = threadIdx.x >> 6;
    const int lane = threadIdx.x & 63;
    const int q_idx = q_base + wave;

    // stage q (scale folded) into LDS, then replicate into registers
    qs[wave][lane] = qkv[(size_t)(b * S_ + q_idx) * 3072 + h * 64 + lane] * 0.125f;
    __syncthreads();
    float qa[64];
#pragma unroll
    for (int d = 0; d < 64; ++d) qa[d] = qs[wave][d];

    float m = -INFINITY, l = 0.f, acc = 0.f;

    const int n_tiles = q_base / 64 + 1;     // (q_base+3)/64 == q_base/64
    const int key_l = threadIdx.x >> 2;      // 0..63 : key within tile
    const int db = (threadIdx.x & 3) * 16;   // 0..48 : dim offset

    for (int t = 0; t < n_tiles; ++t) {
        __syncthreads();   // protect Vs reads of previous iteration
        const float* kg = qkv + (size_t)(b * S_ + t * 64 + key_l) * 3072
                          + 1024 + h * 64 + db;
#pragma unroll
        for (int c = 0; c < 16; c += 4) {
            float4 k4 = *(const float4*)(kg + c);
            float4 v4 = *(const float4*)(kg + 1024 + c);
            Ks[key_l][db + c + 0] = k4.x;
            Ks[key_l][db + c + 1] = k4.y;
            Ks[key_l][db + c + 2] = k4.z;
            Ks[key_l][db + c + 3] = k4.w;
            Vs[key_l][db + c + 0] = v4.x;
            Vs[key_l][db + c + 1] = v4.y;
            Vs[key_l][db + c + 2] = v4.z;
            Vs[key_l][db + c + 3] = v4.w;
        }
        __syncthreads();

        // ---- Phase A: lane = key ----
        const int key = t * 64 + lane;
        float sum = 0.f;
#pragma unroll
        for (int d = 0; d < 64; ++d)
            sum = fmaf(qa[d], Ks[lane][d], sum);
        float s = (key <= q_idx) ? sum : -INFINITY;

        // tile max over 64 lanes
        float tmax = s;
#pragma unroll
        for (int off = 32; off > 0; off >>= 1)
            tmax = fmaxf(tmax, __shfl_xor(tmax, off, 64));
        const float mn = fmaxf(m, tmax);     // finite: key==t*64 always valid

        float p = __expf(s - mn);            // masked lanes -> exp(-inf) = 0
        float psum = p;
#pragma unroll
        for (int off = 32; off > 0; off >>= 1)
            psum += __shfl_xor(psum, off, 64);

        const float alpha = __expf(m - mn);  // first tile: exp(-inf) = 0
        l = l * alpha + psum;
        m = mn;

        // ---- Phase B: lane = dim ----
        float a2 = acc * alpha;
#pragma unroll
        for (int j = 0; j < 64; ++j) {
            float pj = __shfl(p, j, 64);     // compile-time j -> v_readlane
            a2 = fmaf(pj, Vs[j][lane], a2);
        }
        acc = a2;
    }

    out[(size_t)(b * S_ + q_idx) * 1024 + h * 64 + lane] = acc / l;
}

// ---------------------------------------------------------------------------
extern "C" void kernel_launch(void* const* d_in, const int* in_sizes, int n_in,
                              void* d_out, int out_size, void* d_ws, size_t ws_size,
                              hipStream_t stream)
{
    const float* x     = (const float*)d_in[0];   // [2,2048,1024]
    const float* w_qkv = (const float*)d_in[1];   // [1024,3072]
    const float* w_out = (const float*)d_in[2];   // [1024,1024]
    float* out = (float*)d_out;                   // [2,2048,1024]

    float* qkv  = (float*)d_ws;                   // 4096*3072 floats (50.3 MB)
    float* attn = qkv + (size_t)4096 * 3072;      // 4096*1024 floats (16.8 MB)

    // 1) qkv = x @ w_qkv
    gemm_f32<<<dim3(3072 / 64, 4096 / 64), 256, 0, stream>>>(
        x, w_qkv, qkv, 4096, 3072, 1024);

    // 2) RoPE in place on q,k
    rope_kernel<<<(4096 * 16 * 32) / 256, 256, 0, stream>>>(qkv);

    // 3) causal attention -> attn [B*S, D] with (h,d) packed
    attn_kernel<<<dim3(S_ / 4, B_ * H_), 256, 0, stream>>>(qkv, attn);

    // 4) out = attn @ w_out
    gemm_f32<<<dim3(1024 / 64, 4096 / 64), 256, 0, stream>>>(
        attn, w_out, out, 4096, 1024, 1024);
}

// Round 3
// 658.298 us; speedup vs baseline: 9.3871x; 3.5097x over previous
//
#include <hip/hip_runtime.h>
#include <math.h>

// Problem constants (B=2, S=2048, D=1024, H=16, hd=64)
#define B_  2
#define S_  2048
#define D_  1024
#define H_  16

typedef short bf16x8 __attribute__((ext_vector_type(8)));
typedef float f32x4  __attribute__((ext_vector_type(4)));

// fp32 -> bf16 bits, round-to-nearest-even (finite inputs only)
__device__ __forceinline__ short f2bf(float f) {
    unsigned u = __builtin_bit_cast(unsigned, f);
    u += 0x7FFFu + ((u >> 16) & 1u);
    return (short)(u >> 16);
}

// ---------------------------------------------------------------------------
// Generic fp32 tiled GEMM: C[M,N] = A[M,K] @ B[K,N], row-major.
// 64x64 tile, BK=16, 256 threads, 4x4 micro-tile per thread.
// ---------------------------------------------------------------------------
__global__ __launch_bounds__(256) void gemm_f32(
    const float* __restrict__ A, const float* __restrict__ Bm,
    float* __restrict__ C, int M, int N, int K)
{
    __shared__ float As[16][68];
    __shared__ float Bs[16][64];

    const int tid = threadIdx.x;
    const int tx = tid & 15;
    const int ty = tid >> 4;
    const int row0 = blockIdx.y * 64;
    const int col0 = blockIdx.x * 64;

    float acc[4][4];
#pragma unroll
    for (int i = 0; i < 4; ++i)
#pragma unroll
        for (int j = 0; j < 4; ++j) acc[i][j] = 0.f;

    const int am = tid >> 2;
    const int ak = (tid & 3) * 4;
    const int bk = tid >> 4;
    const int bn = (tid & 15) * 4;

    for (int k0 = 0; k0 < K; k0 += 16) {
        float4 a4 = *(const float4*)(A + (size_t)(row0 + am) * K + k0 + ak);
        float4 b4 = *(const float4*)(Bm + (size_t)(k0 + bk) * N + col0 + bn);
        As[ak + 0][am] = a4.x;
        As[ak + 1][am] = a4.y;
        As[ak + 2][am] = a4.z;
        As[ak + 3][am] = a4.w;
        *(float4*)&Bs[bk][bn] = b4;
        __syncthreads();

#pragma unroll
        for (int kk = 0; kk < 16; ++kk) {
            float a0 = As[kk][ty * 4 + 0];
            float a1 = As[kk][ty * 4 + 1];
            float a2 = As[kk][ty * 4 + 2];
            float a3 = As[kk][ty * 4 + 3];
            float4 bb = *(float4*)&Bs[kk][tx * 4];
            acc[0][0] = fmaf(a0, bb.x, acc[0][0]);
            acc[0][1] = fmaf(a0, bb.y, acc[0][1]);
            acc[0][2] = fmaf(a0, bb.z, acc[0][2]);
            acc[0][3] = fmaf(a0, bb.w, acc[0][3]);
            acc[1][0] = fmaf(a1, bb.x, acc[1][0]);
            acc[1][1] = fmaf(a1, bb.y, acc[1][1]);
            acc[1][2] = fmaf(a1, bb.z, acc[1][2]);
            acc[1][3] = fmaf(a1, bb.w, acc[1][3]);
            acc[2][0] = fmaf(a2, bb.x, acc[2][0]);
            acc[2][1] = fmaf(a2, bb.y, acc[2][1]);
            acc[2][2] = fmaf(a2, bb.z, acc[2][2]);
            acc[2][3] = fmaf(a2, bb.w, acc[2][3]);
            acc[3][0] = fmaf(a3, bb.x, acc[3][0]);
            acc[3][1] = fmaf(a3, bb.y, acc[3][1]);
            acc[3][2] = fmaf(a3, bb.z, acc[3][2]);
            acc[3][3] = fmaf(a3, bb.w, acc[3][3]);
        }
        __syncthreads();
    }

#pragma unroll
    for (int i = 0; i < 4; ++i) {
        float4 o = make_float4(acc[i][0], acc[i][1], acc[i][2], acc[i][3]);
        *(float4*)(C + (size_t)(row0 + ty * 4 + i) * N + col0 + tx * 4) = o;
    }
}

// ---------------------------------------------------------------------------
// Convert: qkv fp32 [4096][3072] -> head-major bf16 buffers:
//   Qb[bh][s][d]  (RoPE applied, *0.125 scale folded)
//   Kb[bh][s][d]  (RoPE applied)
//   Vt[bh][d][s]  (transposed via LDS, for PV B-operand contiguity)
// Block = 256 threads handles one (bh, 64-row s-tile).
// ---------------------------------------------------------------------------
__global__ __launch_bounds__(256) void convert_kernel(
    const float* __restrict__ qkv,
    short* __restrict__ Qb, short* __restrict__ Kb, short* __restrict__ Vt)
{
    __shared__ short vtile[64][72];
    const int bh = blockIdx.y;
    const int st = blockIdx.x;
    const int b = bh >> 4, h = bh & 15;

    const int sl = threadIdx.x >> 2;   // s within tile
    const int g  = threadIdx.x & 3;    // group of 8 pairs / 16 dims
    const int s  = st * 64 + sl;
    const float* row = qkv + (size_t)(b * S_ + s) * 3072 + h * 64;

    // ---- q,k RoPE on pairs j0..j0+7 (dims j and j+32) ----
    const int j0 = g * 8;
    bf16x8 qlo, qhi, klo, khi;
#pragma unroll
    for (int i = 0; i < 8; ++i) {
        float jj = (float)(j0 + i);
        float inv = powf(10000.0f, -jj * (1.0f / 32.0f));
        float sn, cs;
        sincosf((float)s * inv, &sn, &cs);
        float q1 = row[j0 + i],        q2 = row[32 + j0 + i];
        float k1 = row[1024 + j0 + i], k2 = row[1056 + j0 + i];
        qlo[i] = f2bf((q1 * cs - q2 * sn) * 0.125f);
        qhi[i] = f2bf((q2 * cs + q1 * sn) * 0.125f);
        klo[i] = f2bf(k1 * cs - k2 * sn);
        khi[i] = f2bf(k2 * cs + k1 * sn);
    }
    size_t o = ((size_t)bh * S_ + s) * 64;
    *(bf16x8*)(Qb + o + j0)      = qlo;
    *(bf16x8*)(Qb + o + 32 + j0) = qhi;
    *(bf16x8*)(Kb + o + j0)      = klo;
    *(bf16x8*)(Kb + o + 32 + j0) = khi;

    // ---- V transpose through LDS ----
#pragma unroll
    for (int i = 0; i < 16; ++i)
        vtile[g * 16 + i][sl] = f2bf(row[2048 + g * 16 + i]);
    __syncthreads();
    size_t vo = ((size_t)bh * 64 + sl) * S_ + st * 64 + g * 16;
    *(bf16x8*)(Vt + vo)     = *(const bf16x8*)&vtile[sl][g * 16];
    *(bf16x8*)(Vt + vo + 8) = *(const bf16x8*)&vtile[sl][g * 16 + 8];
}

// ---------------------------------------------------------------------------
// MFMA flash attention. Block = 4 waves; wave w owns queries [w*16,w*16+16)
// of a 64-query tile. 64-key K/V tiles in LDS, padded to stride 72 bf16.
// mfma_f32_16x16x32_bf16 layouts (m89/m120-verified):
//   A[m=lane&15][k=quad*8+j], B[k=quad*8+j][n=lane&15],
//   C/D[row=quad*4+reg][col=lane&15]
// QK^T: A=Q (global b128), B=K^T from Ks[key][d] rows.
// P: C-layout -> bf16 -> LDS (wave-private rows) -> A-layout b128 reads.
// PV:  B=V from Vs[dim][key] rows (pre-transposed V).
// grid = (S/64, B*H)
// ---------------------------------------------------------------------------
__global__ __launch_bounds__(256) void attn_kernel(
    const short* __restrict__ Qb, const short* __restrict__ Kb,
    const short* __restrict__ Vt, float* __restrict__ out)
{
    __shared__ short Ks[64][72];   // [key][dim]
    __shared__ short Vs[64][72];   // [dim][key]
    __shared__ short Ps[64][72];   // [query][key]

    const int bh = blockIdx.y;
    const int qb = blockIdx.x;
    const int wave = threadIdx.x >> 6;
    const int lane = threadIdx.x & 63;
    const int quad = lane >> 4;
    const int l16  = lane & 15;

    const size_t head = (size_t)bh * S_ * 64;

    // Q A-frags straight from global (row-major, 16B aligned)
    const short* qrow = Qb + head + (size_t)(qb * 64 + wave * 16 + l16) * 64 + quad * 8;
    const bf16x8 qf0 = *(const bf16x8*)(qrow);
    const bf16x8 qf1 = *(const bf16x8*)(qrow + 32);

    float m_r[4], l_r[4];
    f32x4 oacc[4];
#pragma unroll
    for (int r = 0; r < 4; ++r) { m_r[r] = -INFINITY; l_r[r] = 0.f; }
#pragma unroll
    for (int nt = 0; nt < 4; ++nt) oacc[nt] = (f32x4)0.f;

    const int sgr = threadIdx.x >> 2;   // staging row (key for Ks, dim for Vs)
    const int sgc = threadIdx.x & 3;    // staging 32B chunk

    for (int t = 0; t <= qb; ++t) {
        __syncthreads();
        {
            const short* kg = Kb + head + (size_t)(t * 64 + sgr) * 64 + sgc * 16;
            bf16x8 k0 = *(const bf16x8*)kg;
            bf16x8 k1 = *(const bf16x8*)(kg + 8);
            const short* vg = Vt + head + (size_t)sgr * S_ + t * 64 + sgc * 16;
            bf16x8 v0 = *(const bf16x8*)vg;
            bf16x8 v1 = *(const bf16x8*)(vg + 8);
            *(bf16x8*)&Ks[sgr][sgc * 16]     = k0;
            *(bf16x8*)&Ks[sgr][sgc * 16 + 8] = k1;
            *(bf16x8*)&Vs[sgr][sgc * 16]     = v0;
            *(bf16x8*)&Vs[sgr][sgc * 16 + 8] = v1;
        }
        __syncthreads();

        // ---- QK^T ----
        f32x4 s4[4];
#pragma unroll
        for (int nt = 0; nt < 4; ++nt) {
            bf16x8 b0 = *(const bf16x8*)&Ks[nt * 16 + l16][quad * 8];
            bf16x8 b1 = *(const bf16x8*)&Ks[nt * 16 + l16][32 + quad * 8];
            f32x4 acc = (f32x4)0.f;
            acc = __builtin_amdgcn_mfma_f32_16x16x32_bf16(qf0, b0, acc, 0, 0, 0);
            acc = __builtin_amdgcn_mfma_f32_16x16x32_bf16(qf1, b1, acc, 0, 0, 0);
            s4[nt] = acc;
        }

        // causal mask: only the diagonal tile needs it
        if (t == qb) {
#pragma unroll
            for (int nt = 0; nt < 4; ++nt)
#pragma unroll
                for (int r = 0; r < 4; ++r)
                    if (nt * 16 + l16 > wave * 16 + quad * 4 + r)
                        s4[nt][r] = -INFINITY;
        }

        // ---- online softmax, per row r = quad*4+r ----
#pragma unroll
        for (int r = 0; r < 4; ++r) {
            float mx = fmaxf(fmaxf(s4[0][r], s4[1][r]), fmaxf(s4[2][r], s4[3][r]));
#pragma unroll
            for (int off = 1; off < 16; off <<= 1)
                mx = fmaxf(mx, __shfl_xor(mx, off, 64));
            float mn = fmaxf(m_r[r], mx);
            float alpha = __expf(m_r[r] - mn);   // first tile: exp(-inf)=0
            m_r[r] = mn;
            float ps = 0.f;
#pragma unroll
            for (int nt = 0; nt < 4; ++nt) {
                float pv = __expf(s4[nt][r] - mn);   // masked: exp(-inf)=0
                s4[nt][r] = pv;
                ps += pv;
            }
#pragma unroll
            for (int off = 1; off < 16; off <<= 1)
                ps += __shfl_xor(ps, off, 64);
            l_r[r] = l_r[r] * alpha + ps;
#pragma unroll
            for (int nt = 0; nt < 4; ++nt) oacc[nt][r] *= alpha;
        }

        // ---- P: C-layout -> bf16 -> LDS (wave-private rows) ----
#pragma unroll
        for (int nt = 0; nt < 4; ++nt)
#pragma unroll
            for (int r = 0; r < 4; ++r)
                Ps[wave * 16 + quad * 4 + r][nt * 16 + l16] = f2bf(s4[nt][r]);

        // ---- PV ----
        bf16x8 pa0 = *(const bf16x8*)&Ps[wave * 16 + l16][quad * 8];
        bf16x8 pa1 = *(const bf16x8*)&Ps[wave * 16 + l16][32 + quad * 8];
#pragma unroll
        for (int nt = 0; nt < 4; ++nt) {
            bf16x8 vb0 = *(const bf16x8*)&Vs[nt * 16 + l16][quad * 8];
            bf16x8 vb1 = *(const bf16x8*)&Vs[nt * 16 + l16][32 + quad * 8];
            oacc[nt] = __builtin_amdgcn_mfma_f32_16x16x32_bf16(pa0, vb0, oacc[nt], 0, 0, 0);
            oacc[nt] = __builtin_amdgcn_mfma_f32_16x16x32_bf16(pa1, vb1, oacc[nt], 0, 0, 0);
        }
    }

    // ---- epilogue: O[q][d] / l, layout [b][s][h*64+d] ----
    const int b = bh >> 4, h = bh & 15;
#pragma unroll
    for (int r = 0; r < 4; ++r) {
        int q = qb * 64 + wave * 16 + quad * 4 + r;
        float invl = 1.0f / l_r[r];
        float* orow = out + (size_t)(b * S_ + q) * 1024 + h * 64;
#pragma unroll
        for (int nt = 0; nt < 4; ++nt)
            orow[nt * 16 + l16] = oacc[nt][r] * invl;
    }
}

// ---------------------------------------------------------------------------
extern "C" void kernel_launch(void* const* d_in, const int* in_sizes, int n_in,
                              void* d_out, int out_size, void* d_ws, size_t ws_size,
                              hipStream_t stream)
{
    const float* x     = (const float*)d_in[0];   // [2,2048,1024]
    const float* w_qkv = (const float*)d_in[1];   // [1024,3072]
    const float* w_out = (const float*)d_in[2];   // [1024,1024]
    float* out = (float*)d_out;                   // [2,2048,1024]

    float* qkv  = (float*)d_ws;                               // 50.3 MB
    short* Qb = (short*)((char*)d_ws + (size_t)4096 * 3072 * 4);  // 8.4 MB
    short* Kb = Qb + (size_t)4096 * 1024;                         // 8.4 MB
    short* Vt = Kb + (size_t)4096 * 1024;                         // 8.4 MB
    float* attn = qkv;   // attention output reuses qkv space (qkv dead by then)

    // 1) qkv = x @ w_qkv
    gemm_f32<<<dim3(3072 / 64, 4096 / 64), 256, 0, stream>>>(
        x, w_qkv, qkv, 4096, 3072, 1024);

    // 2) RoPE + bf16 convert + V transpose
    convert_kernel<<<dim3(S_ / 64, B_ * H_), 256, 0, stream>>>(qkv, Qb, Kb, Vt);

    // 3) MFMA flash attention -> attn [B*S, D] (h,d packed)
    attn_kernel<<<dim3(S_ / 64, B_ * H_), 256, 0, stream>>>(Qb, Kb, Vt, attn);

    // 4) out = attn @ w_out
    gemm_f32<<<dim3(1024 / 64, 4096 / 64), 256, 0, stream>>>(
        attn, w_out, out, 4096, 1024, 1024);
}

// Round 4
// 270.566 us; speedup vs baseline: 22.8392x; 2.4330x over previous
//
#include <hip/hip_runtime.h>
#include <math.h>
#include <type_traits>

// Problem constants (B=2, S=2048, D=1024, H=16, hd=64)
#define B_  2
#define S_  2048
#define D_  1024
#define H_  16

typedef short bf16x8 __attribute__((ext_vector_type(8)));
typedef float f32x4  __attribute__((ext_vector_type(4)));

// fp32 -> bf16 bits, round-to-nearest-even (finite inputs only)
__device__ __forceinline__ short f2bf(float f) {
    unsigned u = __builtin_bit_cast(unsigned, f);
    u += 0x7FFFu + ((u >> 16) & 1u);
    return (short)(u >> 16);
}
__device__ __forceinline__ float bf2f(short s) {
    unsigned u = ((unsigned)(unsigned short)s) << 16;
    return __builtin_bit_cast(float, u);
}

// async global->LDS, 16B per lane; LDS dest = wave-uniform base + lane*16
__device__ __forceinline__ void gload16(const short* g, const void* l) {
    __builtin_amdgcn_global_load_lds(
        (const __attribute__((address_space(1))) void*)g,
        (__attribute__((address_space(3))) void*)l, 16, 0, 0);
}

// ---------------------------------------------------------------------------
// fp32 -> bf16 elementwise (8 elems/thread)
// ---------------------------------------------------------------------------
__global__ __launch_bounds__(256) void cvt_bf16_kernel(
    const float* __restrict__ in, short* __restrict__ out)
{
    int i = (blockIdx.x * 256 + threadIdx.x) * 8;
    float4 a = *(const float4*)(in + i);
    float4 b = *(const float4*)(in + i + 4);
    bf16x8 o;
    o[0] = f2bf(a.x); o[1] = f2bf(a.y); o[2] = f2bf(a.z); o[3] = f2bf(a.w);
    o[4] = f2bf(b.x); o[5] = f2bf(b.y); o[6] = f2bf(b.z); o[7] = f2bf(b.w);
    *(bf16x8*)(out + i) = o;
}

// ---------------------------------------------------------------------------
// fp32 [K][N] -> bf16 [N][K] transpose via LDS. Grid (N/64, K/64).
// ---------------------------------------------------------------------------
__global__ __launch_bounds__(256) void transpose_cvt_kernel(
    const float* __restrict__ in, short* __restrict__ out, int K, int N)
{
    __shared__ short t[64][72];
    const int k0 = blockIdx.y * 64, n0 = blockIdx.x * 64;
    const int r = threadIdx.x >> 2;
    const int c = (threadIdx.x & 3) * 16;
    const float* src = in + (size_t)(k0 + r) * N + n0 + c;
#pragma unroll
    for (int i = 0; i < 16; ++i) t[c + i][r] = f2bf(src[i]);
    __syncthreads();
    short* dst = out + (size_t)(n0 + r) * K + k0 + c;
    *(bf16x8*)(dst)     = *(const bf16x8*)&t[r][c];
    *(bf16x8*)(dst + 8) = *(const bf16x8*)&t[r][c + 8];
}

// ---------------------------------------------------------------------------
// RoPE cos/sin table: tab[s*32+j] = (cos, sin) of s / 10000^(j/32)
// ---------------------------------------------------------------------------
__global__ __launch_bounds__(256) void rope_tab_kernel(float2* __restrict__ tab)
{
    int idx = blockIdx.x * 256 + threadIdx.x;   // < 2048*32
    int j = idx & 31, s = idx >> 5;
    float inv = powf(10000.0f, -(float)j * (1.0f / 32.0f));
    float sn, cs;
    sincosf((float)s * inv, &sn, &cs);
    tab[idx] = make_float2(cs, sn);
}

// ---------------------------------------------------------------------------
// bf16 MFMA GEMM (m97 structure): C[M,N] = A[M,K] @ Bt[N,K]^T.
// 128x128 tile, BK=32, 256 thr = 4 waves (2x2), 4x4 MFMAs of 16x16x32/wave.
// global_load_lds width 16, unpadded lane-linear LDS ([row][32] bf16).
// ---------------------------------------------------------------------------
template <typename OutT>
__global__ __launch_bounds__(256) void gemm_bt(
    const short* __restrict__ A, const short* __restrict__ Bt,
    OutT* __restrict__ C, int M, int N, int K)
{
    __shared__ short As[128 * 32];
    __shared__ short Bs[128 * 32];

    const int tid  = threadIdx.x;
    const int wave = tid >> 6, lane = tid & 63;
    const int quad = lane >> 4, l16 = lane & 15;
    const int wm = wave >> 1, wn = wave & 1;
    const int row0 = blockIdx.y * 128, col0 = blockIdx.x * 128;

    f32x4 acc[4][4];
#pragma unroll
    for (int mi = 0; mi < 4; ++mi)
#pragma unroll
        for (int ni = 0; ni < 4; ++ni) acc[mi][ni] = (f32x4)0.f;

    const int sr = tid >> 2;            // staging row 0..63
    const int sc = (tid & 3) * 8;       // staging k-chunk (shorts)
    const short* a0 = A  + (size_t)(row0 + sr) * K + sc;
    const short* a1 = A  + (size_t)(row0 + 64 + sr) * K + sc;
    const short* b0 = Bt + (size_t)(col0 + sr) * K + sc;
    const short* b1 = Bt + (size_t)(col0 + 64 + sr) * K + sc;
    char* lA0 = (char*)As + wave * 1024;
    char* lA1 = (char*)As + 4096 + wave * 1024;
    char* lB0 = (char*)Bs + wave * 1024;
    char* lB1 = (char*)Bs + 4096 + wave * 1024;

    for (int k0 = 0; k0 < K; k0 += 32) {
        __syncthreads();
        gload16(a0 + k0, lA0);
        gload16(a1 + k0, lA1);
        gload16(b0 + k0, lB0);
        gload16(b1 + k0, lB1);
        __syncthreads();

        bf16x8 af[4], bfr[4];
#pragma unroll
        for (int mi = 0; mi < 4; ++mi)
            af[mi] = *(const bf16x8*)(As + (wm * 64 + mi * 16 + l16) * 32 + quad * 8);
#pragma unroll
        for (int ni = 0; ni < 4; ++ni)
            bfr[ni] = *(const bf16x8*)(Bs + (wn * 64 + ni * 16 + l16) * 32 + quad * 8);
#pragma unroll
        for (int mi = 0; mi < 4; ++mi)
#pragma unroll
            for (int ni = 0; ni < 4; ++ni)
                acc[mi][ni] = __builtin_amdgcn_mfma_f32_16x16x32_bf16(
                    af[mi], bfr[ni], acc[mi][ni], 0, 0, 0);
    }

    // epilogue: C[row=quad*4+r][col=l16] per 16x16 tile
#pragma unroll
    for (int mi = 0; mi < 4; ++mi) {
#pragma unroll
        for (int ni = 0; ni < 4; ++ni) {
#pragma unroll
            for (int r = 0; r < 4; ++r) {
                int row = row0 + wm * 64 + mi * 16 + quad * 4 + r;
                int col = col0 + wn * 64 + ni * 16 + l16;
                float v = acc[mi][ni][r];
                if constexpr (std::is_same_v<OutT, short>)
                    C[(size_t)row * N + col] = f2bf(v);
                else
                    C[(size_t)row * N + col] = v;
            }
        }
    }
}

// ---------------------------------------------------------------------------
// Convert: qkvb bf16 [4096][3072] -> head-major bf16 buffers:
//   Qb[bh][s][d] (RoPE, *0.125), Kb[bh][s][d] (RoPE), Vt[bh][d][s] (transposed)
// ---------------------------------------------------------------------------
__global__ __launch_bounds__(256) void convert_kernel(
    const short* __restrict__ qkvb, const float2* __restrict__ tab,
    short* __restrict__ Qb, short* __restrict__ Kb, short* __restrict__ Vt)
{
    __shared__ short vtile[64][72];
    const int bh = blockIdx.y;
    const int st = blockIdx.x;
    const int b = bh >> 4, h = bh & 15;

    const int sl = threadIdx.x >> 2;   // s within tile
    const int g  = threadIdx.x & 3;    // group of 8 pairs / 16 dims
    const int s  = st * 64 + sl;
    const short* row = qkvb + (size_t)(b * S_ + s) * 3072 + h * 64;

    const int j0 = g * 8;
    bf16x8 q1v = *(const bf16x8*)(row + j0);
    bf16x8 q2v = *(const bf16x8*)(row + 32 + j0);
    bf16x8 k1v = *(const bf16x8*)(row + 1024 + j0);
    bf16x8 k2v = *(const bf16x8*)(row + 1056 + j0);
    bf16x8 qlo, qhi, klo, khi;
#pragma unroll
    for (int i = 0; i < 8; ++i) {
        float2 t = tab[s * 32 + j0 + i];
        float q1 = bf2f(q1v[i]), q2 = bf2f(q2v[i]);
        float k1 = bf2f(k1v[i]), k2 = bf2f(k2v[i]);
        qlo[i] = f2bf((q1 * t.x - q2 * t.y) * 0.125f);
        qhi[i] = f2bf((q2 * t.x + q1 * t.y) * 0.125f);
        klo[i] = f2bf(k1 * t.x - k2 * t.y);
        khi[i] = f2bf(k2 * t.x + k1 * t.y);
    }
    size_t o = ((size_t)bh * S_ + s) * 64;
    *(bf16x8*)(Qb + o + j0)      = qlo;
    *(bf16x8*)(Qb + o + 32 + j0) = qhi;
    *(bf16x8*)(Kb + o + j0)      = klo;
    *(bf16x8*)(Kb + o + 32 + j0) = khi;

    // V transpose through LDS (bf16 passthrough)
    bf16x8 v0 = *(const bf16x8*)(row + 2048 + g * 16);
    bf16x8 v1 = *(const bf16x8*)(row + 2048 + g * 16 + 8);
#pragma unroll
    for (int i = 0; i < 8; ++i) {
        vtile[g * 16 + i][sl]     = v0[i];
        vtile[g * 16 + 8 + i][sl] = v1[i];
    }
    __syncthreads();
    size_t vo = ((size_t)bh * 64 + sl) * S_ + st * 64 + g * 16;
    *(bf16x8*)(Vt + vo)     = *(const bf16x8*)&vtile[sl][g * 16];
    *(bf16x8*)(Vt + vo + 8) = *(const bf16x8*)&vtile[sl][g * 16 + 8];
}

// ---------------------------------------------------------------------------
// MFMA flash attention (as R3), epilogue writes bf16.
// grid = (S/64, B*H), block = 256.
// ---------------------------------------------------------------------------
__global__ __launch_bounds__(256) void attn_kernel(
    const short* __restrict__ Qb, const short* __restrict__ Kb,
    const short* __restrict__ Vt, short* __restrict__ attnb)
{
    __shared__ short Ks[64][72];   // [key][dim]
    __shared__ short Vs[64][72];   // [dim][key]
    __shared__ short Ps[64][72];   // [query][key]

    const int bh = blockIdx.y;
    const int qb = blockIdx.x;
    const int wave = threadIdx.x >> 6;
    const int lane = threadIdx.x & 63;
    const int quad = lane >> 4;
    const int l16  = lane & 15;

    const size_t head = (size_t)bh * S_ * 64;

    const short* qrow = Qb + head + (size_t)(qb * 64 + wave * 16 + l16) * 64 + quad * 8;
    const bf16x8 qf0 = *(const bf16x8*)(qrow);
    const bf16x8 qf1 = *(const bf16x8*)(qrow + 32);

    float m_r[4], l_r[4];
    f32x4 oacc[4];
#pragma unroll
    for (int r = 0; r < 4; ++r) { m_r[r] = -INFINITY; l_r[r] = 0.f; }
#pragma unroll
    for (int nt = 0; nt < 4; ++nt) oacc[nt] = (f32x4)0.f;

    const int sgr = threadIdx.x >> 2;
    const int sgc = threadIdx.x & 3;

    for (int t = 0; t <= qb; ++t) {
        __syncthreads();
        {
            const short* kg = Kb + head + (size_t)(t * 64 + sgr) * 64 + sgc * 16;
            bf16x8 k0 = *(const bf16x8*)kg;
            bf16x8 k1 = *(const bf16x8*)(kg + 8);
            const short* vg = Vt + head + (size_t)sgr * S_ + t * 64 + sgc * 16;
            bf16x8 v0 = *(const bf16x8*)vg;
            bf16x8 v1 = *(const bf16x8*)(vg + 8);
            *(bf16x8*)&Ks[sgr][sgc * 16]     = k0;
            *(bf16x8*)&Ks[sgr][sgc * 16 + 8] = k1;
            *(bf16x8*)&Vs[sgr][sgc * 16]     = v0;
            *(bf16x8*)&Vs[sgr][sgc * 16 + 8] = v1;
        }
        __syncthreads();

        // QK^T
        f32x4 s4[4];
#pragma unroll
        for (int nt = 0; nt < 4; ++nt) {
            bf16x8 b0 = *(const bf16x8*)&Ks[nt * 16 + l16][quad * 8];
            bf16x8 b1 = *(const bf16x8*)&Ks[nt * 16 + l16][32 + quad * 8];
            f32x4 acc = (f32x4)0.f;
            acc = __builtin_amdgcn_mfma_f32_16x16x32_bf16(qf0, b0, acc, 0, 0, 0);
            acc = __builtin_amdgcn_mfma_f32_16x16x32_bf16(qf1, b1, acc, 0, 0, 0);
            s4[nt] = acc;
        }

        if (t == qb) {
#pragma unroll
            for (int nt = 0; nt < 4; ++nt)
#pragma unroll
                for (int r = 0; r < 4; ++r)
                    if (nt * 16 + l16 > wave * 16 + quad * 4 + r)
                        s4[nt][r] = -INFINITY;
        }

        // online softmax per row r
#pragma unroll
        for (int r = 0; r < 4; ++r) {
            float mx = fmaxf(fmaxf(s4[0][r], s4[1][r]), fmaxf(s4[2][r], s4[3][r]));
#pragma unroll
            for (int off = 1; off < 16; off <<= 1)
                mx = fmaxf(mx, __shfl_xor(mx, off, 64));
            float mn = fmaxf(m_r[r], mx);
            float alpha = __expf(m_r[r] - mn);
            m_r[r] = mn;
            float ps = 0.f;
#pragma unroll
            for (int nt = 0; nt < 4; ++nt) {
                float pv = __expf(s4[nt][r] - mn);
                s4[nt][r] = pv;
                ps += pv;
            }
#pragma unroll
            for (int off = 1; off < 16; off <<= 1)
                ps += __shfl_xor(ps, off, 64);
            l_r[r] = l_r[r] * alpha + ps;
#pragma unroll
            for (int nt = 0; nt < 4; ++nt) oacc[nt][r] *= alpha;
        }

        // P -> LDS (wave-private rows)
#pragma unroll
        for (int nt = 0; nt < 4; ++nt)
#pragma unroll
            for (int r = 0; r < 4; ++r)
                Ps[wave * 16 + quad * 4 + r][nt * 16 + l16] = f2bf(s4[nt][r]);

        // PV
        bf16x8 pa0 = *(const bf16x8*)&Ps[wave * 16 + l16][quad * 8];
        bf16x8 pa1 = *(const bf16x8*)&Ps[wave * 16 + l16][32 + quad * 8];
#pragma unroll
        for (int nt = 0; nt < 4; ++nt) {
            bf16x8 vb0 = *(const bf16x8*)&Vs[nt * 16 + l16][quad * 8];
            bf16x8 vb1 = *(const bf16x8*)&Vs[nt * 16 + l16][32 + quad * 8];
            oacc[nt] = __builtin_amdgcn_mfma_f32_16x16x32_bf16(pa0, vb0, oacc[nt], 0, 0, 0);
            oacc[nt] = __builtin_amdgcn_mfma_f32_16x16x32_bf16(pa1, vb1, oacc[nt], 0, 0, 0);
        }
    }

    // epilogue -> bf16, layout [b][s][h*64+d]
    const int b = bh >> 4, h = bh & 15;
#pragma unroll
    for (int r = 0; r < 4; ++r) {
        int q = qb * 64 + wave * 16 + quad * 4 + r;
        float invl = 1.0f / l_r[r];
        short* orow = attnb + (size_t)(b * S_ + q) * 1024 + h * 64;
#pragma unroll
        for (int nt = 0; nt < 4; ++nt)
            orow[nt * 16 + l16] = f2bf(oacc[nt][r] * invl);
    }
}

// ---------------------------------------------------------------------------
extern "C" void kernel_launch(void* const* d_in, const int* in_sizes, int n_in,
                              void* d_out, int out_size, void* d_ws, size_t ws_size,
                              hipStream_t stream)
{
    const float* x     = (const float*)d_in[0];   // [2,2048,1024]
    const float* w_qkv = (const float*)d_in[1];   // [1024,3072]
    const float* w_out = (const float*)d_in[2];   // [1024,1024]
    float* out = (float*)d_out;                   // [2,2048,1024]

    // workspace layout (bf16 shorts unless noted)
    short* qkvb = (short*)d_ws;                       // [4096][3072]  25.2 MB
    short* Qb   = qkvb + (size_t)4096 * 3072;         // [32][2048][64] 8.4 MB
    short* Kb   = Qb   + (size_t)4096 * 1024;         //                8.4 MB
    short* Vt   = Kb   + (size_t)4096 * 1024;         // [32][64][2048] 8.4 MB
    short* Xb   = Vt   + (size_t)4096 * 1024;         // [4096][1024]   8.4 MB
    short* Wqt  = Xb   + (size_t)4096 * 1024;         // [3072][1024]   6.3 MB
    short* Wot  = Wqt  + (size_t)3072 * 1024;         // [1024][1024]   2.1 MB
    float2* tab = (float2*)(Wot + (size_t)1024 * 1024); // [2048*32]    0.5 MB
    short* attnb = Xb;   // Xb dead after gemm1; reuse for attention output

    // 1) conversions / transposes / RoPE table
    cvt_bf16_kernel<<<(4096 * 1024 / 8) / 256, 256, 0, stream>>>(x, Xb);
    transpose_cvt_kernel<<<dim3(3072 / 64, 1024 / 64), 256, 0, stream>>>(
        w_qkv, Wqt, 1024, 3072);
    transpose_cvt_kernel<<<dim3(1024 / 64, 1024 / 64), 256, 0, stream>>>(
        w_out, Wot, 1024, 1024);
    rope_tab_kernel<<<(2048 * 32) / 256, 256, 0, stream>>>(tab);

    // 2) qkvb = Xb @ Wqt^T  (bf16 out)
    gemm_bt<short><<<dim3(3072 / 128, 4096 / 128), 256, 0, stream>>>(
        Xb, Wqt, qkvb, 4096, 3072, 1024);

    // 3) RoPE + head-major repack + V transpose
    convert_kernel<<<dim3(S_ / 64, B_ * H_), 256, 0, stream>>>(qkvb, tab, Qb, Kb, Vt);

    // 4) MFMA flash attention -> attnb bf16 [4096][1024] (h,d packed)
    attn_kernel<<<dim3(S_ / 64, B_ * H_), 256, 0, stream>>>(Qb, Kb, Vt, attnb);

    // 5) out = attnb @ Wot^T  (fp32 out)
    gemm_bt<float><<<dim3(1024 / 128, 4096 / 128), 256, 0, stream>>>(
        attnb, Wot, out, 4096, 1024, 1024);
}